// Round 3
// baseline (686.461 us; speedup 1.0000x reference)
//
#include <hip/hip_runtime.h>
#include <cmath>

typedef __attribute__((ext_vector_type(8))) __bf16 v8bf;
typedef __attribute__((ext_vector_type(4))) float  v4f;

#define DEV static __device__ __forceinline__

DEV unsigned short f2bf(float f) {
  unsigned u = __builtin_bit_cast(unsigned, f);
  unsigned r = u + 0x7fffu + ((u >> 16) & 1u);   // RNE
  return (unsigned short)(r >> 16);
}
DEV float bf2f(unsigned short s) {
  return __builtin_bit_cast(float, ((unsigned)s) << 16);
}
DEV v8bf ld8(const unsigned short* p) { return *(const v8bf*)p; }

// async global->LDS, 16 B per lane; LDS dest = wave-uniform base + lane*16
DEV void gl16(const unsigned short* g, unsigned short* l) {
  __builtin_amdgcn_global_load_lds(
      (const __attribute__((address_space(1))) unsigned int*)g,
      (__attribute__((address_space(3))) unsigned int*)l, 16, 0, 0);
}

// ---------------- prep kernels ----------------
__global__ __launch_bounds__(256) void k_cvt_x(const float* __restrict__ x,
                                               unsigned short* __restrict__ xb) {
  int i = blockIdx.x * 256 + threadIdx.x;          // grid 4096
  float4 v = ((const float4*)x)[i];
  unsigned lo = (unsigned)f2bf(v.x) | ((unsigned)f2bf(v.y) << 16);
  unsigned hi = (unsigned)f2bf(v.z) | ((unsigned)f2bf(v.w) << 16);
  ((uint2*)xb)[i] = make_uint2(lo, hi);
}

// dst[n][k] = (bf16) src[k][n]; z selects which weight matrix
__global__ __launch_bounds__(256) void k_trans_w4(const float* __restrict__ Wq,
                                                  const float* __restrict__ Wk,
                                                  const float* __restrict__ Wv,
                                                  const float* __restrict__ Wo,
                                                  unsigned short* __restrict__ WT,
                                                  unsigned short* __restrict__ WoT) {
  __shared__ float t[32][33];
  int z = blockIdx.z;
  const float* src = (z == 0) ? Wq : (z == 1) ? Wk : (z == 2) ? Wv : Wo;
  unsigned short* dst = (z < 3) ? WT + z * 1048576 : WoT;
  int n0 = blockIdx.x * 32, k0 = blockIdx.y * 32;
  int tx = threadIdx.x & 31, ty = threadIdx.x >> 5;
  for (int r = ty; r < 32; r += 8)
    t[r][tx] = src[(k0 + r) * 1024 + n0 + tx];
  __syncthreads();
  for (int r = ty; r < 32; r += 8)
    dst[(n0 + r) * 1024 + k0 + tx] = f2bf(t[tx][r]);
}

__global__ __launch_bounds__(256) void k_bias(const float* __restrict__ bq,
                                              const float* __restrict__ bk,
                                              const float* __restrict__ bv,
                                              float* __restrict__ dst) {
  int i = blockIdx.x * 256 + threadIdx.x;          // grid 12 -> 3072
  float v = (i < 1024) ? bq[i] : (i < 2048 ? bk[i - 1024] : bv[i - 2048]);
  dst[i] = v;
}

// ---------------- bf16 MFMA GEMM (m97 structure): C = A * Bt^T + bias ----------------
// 128x128 tile, BK=32, global_load_lds width-16 staging, 4 waves each 64x64.
template <bool OUT_F32>
__global__ __launch_bounds__(256) void k_gemm(const unsigned short* __restrict__ A,
                                              const unsigned short* __restrict__ Bt,
                                              const float* __restrict__ bias,
                                              void* __restrict__ Cout,
                                              int ldc) {
  constexpr int K = 1024;
  __shared__ __attribute__((aligned(16))) unsigned short As[128 * 32];
  __shared__ __attribute__((aligned(16))) unsigned short Bs[128 * 32];
  int tid = threadIdx.x;
  int wave = tid >> 6, lane = tid & 63;
  int m0 = blockIdx.y * 128, n0 = blockIdx.x * 128;
  int wm = (wave >> 1) * 64, wn = (wave & 1) * 64;
  int m = lane & 15, q4 = lane >> 4;
  int arow = tid >> 2, acol = (tid & 3) * 8;       // lane's 16 B slot; As byte off = tid*16
  v4f acc[4][4] = {};
  const unsigned short* ga0 = A + (m0 + arow) * K + acol;
  const unsigned short* ga1 = A + (m0 + 64 + arow) * K + acol;
  const unsigned short* gb0 = Bt + (n0 + arow) * K + acol;
  const unsigned short* gb1 = Bt + (n0 + 64 + arow) * K + acol;
  // wave-uniform LDS bases: wave w covers rows [w*16, w*16+16) => byte w*1024
  unsigned short* lA0 = As + wave * 512;
  unsigned short* lA1 = As + 2048 + wave * 512;    // rows 64.. start at elem 64*32
  unsigned short* lB0 = Bs + wave * 512;
  unsigned short* lB1 = Bs + 2048 + wave * 512;

  for (int kt = 0; kt < K; kt += 32) {
    gl16(ga0 + kt, lA0);
    gl16(ga1 + kt, lA1);
    gl16(gb0 + kt, lB0);
    gl16(gb1 + kt, lB1);
    __syncthreads();                               // drains vmcnt(0) then barrier
    v8bf af[4], bfv[4];
#pragma unroll
    for (int mt = 0; mt < 4; mt++) af[mt] = ld8(&As[(wm + mt * 16 + m) * 32 + q4 * 8]);
#pragma unroll
    for (int nt = 0; nt < 4; nt++) bfv[nt] = ld8(&Bs[(wn + nt * 16 + m) * 32 + q4 * 8]);
#pragma unroll
    for (int mt = 0; mt < 4; mt++)
#pragma unroll
      for (int nt = 0; nt < 4; nt++)
        acc[mt][nt] = __builtin_amdgcn_mfma_f32_16x16x32_bf16(af[mt], bfv[nt], acc[mt][nt], 0, 0, 0);
    __syncthreads();                               // reads done before next overwrite
  }
  // epilogue: C/D layout row=(lane>>4)*4+r, col=lane&15
#pragma unroll
  for (int mt = 0; mt < 4; mt++)
#pragma unroll
    for (int nt = 0; nt < 4; nt++) {
      int col = n0 + wn + nt * 16 + m;
      float bb = bias[col];
#pragma unroll
      for (int r = 0; r < 4; r++) {
        int row = m0 + wm + mt * 16 + q4 * 4 + r;
        float v = acc[mt][nt][r] + bb;
        if (OUT_F32) ((float*)Cout)[row * ldc + col] = v;
        else ((unsigned short*)Cout)[row * ldc + col] = f2bf(v);
      }
    }
}

// ---------------- sliding-window attention (band only) ----------------
// QKV bf16 [4096][3072]. One block = (b, h, 64 queries), 4 waves x 16 q.
// Writes Oatt bf16 [4096][1024] and compact band cb[(b*16+h)*2048+i][128] bf16
// (w -> key j = i-127+w; masked entries are 0 from the softmax).
__global__ __launch_bounds__(256) void k_attn(const unsigned short* __restrict__ QKV,
                                              unsigned short* __restrict__ Oatt,
                                              unsigned short* __restrict__ cb) {
  constexpr int VTS = 208;   // Vt row stride (elems)
  constexpr int PSS = 168;   // Ps row stride (elems)
  __shared__ __attribute__((aligned(16))) unsigned short Vt[64 * VTS];       // 26.6 KB
  __shared__ __attribute__((aligned(16))) unsigned short Ps[4][16 * PSS];    // 21.5 KB
  int b = blockIdx.z, h = blockIdx.y, i0 = blockIdx.x * 64;
  int tid = threadIdx.x, wave = tid >> 6, lane = tid & 63;
  int kbase = i0 - 128;
  const int ld = 3072;
  const unsigned short* Qg = QKV + b * 2048 * ld + h * 64;
  const unsigned short* Kg = Qg + 1024;
  const unsigned short* Vg = Qg + 2048;

  // stage V transposed: Vt[d][j], keys [kbase, kbase+192).
  // j in the low 4 bits of c -> LDS store banks spread by j (was 16-way conflict).
  for (int c = tid; c < 192 * 16; c += 256) {
    int jl = c & 15, rest = c >> 4;
    int d0 = (rest & 15) * 4;
    int j = (rest >> 4) * 16 + jl;
    int jg = kbase + j; jg = jg < 0 ? 0 : jg;      // clamp; mask kills j<0
    uint2 v = *(const uint2*)(Vg + jg * ld + d0);
    Vt[(d0 + 0) * VTS + j] = (unsigned short)(v.x & 0xffffu);
    Vt[(d0 + 1) * VTS + j] = (unsigned short)(v.x >> 16);
    Vt[(d0 + 2) * VTS + j] = (unsigned short)(v.y & 0xffffu);
    Vt[(d0 + 3) * VTS + j] = (unsigned short)(v.y >> 16);
  }
  // zero Vt cols [192,208): wave3's PV c=4 chunk reads them (0 x garbage = NaN fix)
  for (int c = tid; c < 64 * 16; c += 256)
    Vt[(c >> 4) * VTS + 192 + (c & 15)] = 0;
  // zero Ps pad cols [144,168) so padded PV chunks contribute 0
  for (int c = lane; c < 16 * 24; c += 64)
    Ps[wave][(c / 24) * PSS + 144 + (c % 24)] = 0;
  __syncthreads();

  int qb = i0 + wave * 16;
  int m = lane & 15, q4 = lane >> 4;

  // Q A-fragments straight from global: A[m=lane&15][k=q4*8+j]
  const unsigned short* qrow = Qg + (qb + m) * ld;
  v8bf qa0 = ld8(qrow + q4 * 8);
  v8bf qa1 = ld8(qrow + 32 + q4 * 8);

  // scores: 9 key tiles of 16 covering keys [qb-128, qb+16)
  v4f sc[9];
#pragma unroll
  for (int n = 0; n < 9; n++) {
    int key = kbase + wave * 16 + n * 16 + m;
    int kg = key < 0 ? 0 : key;
    const unsigned short* krow = Kg + kg * ld;
    v8bf kb0 = ld8(krow + q4 * 8);
    v8bf kb1 = ld8(krow + 32 + q4 * 8);
    v4f z = {0.f, 0.f, 0.f, 0.f};
    z = __builtin_amdgcn_mfma_f32_16x16x32_bf16(qa0, kb0, z, 0, 0, 0);
    z = __builtin_amdgcn_mfma_f32_16x16x32_bf16(qa1, kb1, z, 0, 0, 0);
    sc[n] = z;
  }
  // mask + scale; softmax. C layout: row=q4*4+r (query), col=m (key)
  float mx[4] = {-3e38f, -3e38f, -3e38f, -3e38f};
#pragma unroll
  for (int n = 0; n < 9; n++)
#pragma unroll
    for (int r = 0; r < 4; r++) {
      int i = qb + q4 * 4 + r;
      int j = kbase + wave * 16 + n * 16 + m;
      float v = sc[n][r] * 0.125f;                 // 1/sqrt(64)
      bool ok = (j >= 0) && (j <= i) && (j > i - 128);
      v = ok ? v : -3e38f;
      sc[n][r] = v;
      mx[r] = fmaxf(mx[r], v);
    }
#pragma unroll
  for (int o = 1; o < 16; o <<= 1)
#pragma unroll
    for (int r = 0; r < 4; r++) mx[r] = fmaxf(mx[r], __shfl_xor(mx[r], o, 64));
  float sum[4] = {0.f, 0.f, 0.f, 0.f};
#pragma unroll
  for (int n = 0; n < 9; n++)
#pragma unroll
    for (int r = 0; r < 4; r++) {
      float p = __expf(sc[n][r] - mx[r]);
      sc[n][r] = p;
      sum[r] += p;
    }
#pragma unroll
  for (int o = 1; o < 16; o <<= 1)
#pragma unroll
    for (int r = 0; r < 4; r++) sum[r] += __shfl_xor(sum[r], o, 64);
  float inv[4];
#pragma unroll
  for (int r = 0; r < 4; r++) inv[r] = 1.0f / sum[r];

  // P -> LDS (A-operand layout source for PV)
#pragma unroll
  for (int n = 0; n < 9; n++)
#pragma unroll
    for (int r = 0; r < 4; r++)
      Ps[wave][(q4 * 4 + r) * PSS + n * 16 + m] = f2bf(sc[n][r] * inv[r]);
  __syncthreads();

  // PV: out[16 q][64 d], 5 key-chunks of 32
  v4f oacc[4] = {};
#pragma unroll
  for (int c = 0; c < 5; c++) {
    v8bf pa = ld8(&Ps[wave][m * PSS + c * 32 + q4 * 8]);
#pragma unroll
    for (int dt = 0; dt < 4; dt++) {
      v8bf vb = ld8(&Vt[(dt * 16 + m) * VTS + wave * 16 + c * 32 + q4 * 8]);
      oacc[dt] = __builtin_amdgcn_mfma_f32_16x16x32_bf16(pa, vb, oacc[dt], 0, 0, 0);
    }
  }
#pragma unroll
  for (int dt = 0; dt < 4; dt++)
#pragma unroll
    for (int r = 0; r < 4; r++)
      Oatt[(b * 2048 + qb + q4 * 4 + r) * 1024 + h * 64 + dt * 16 + m] = f2bf(oacc[dt][r]);

  // compact band out: row i, w in [0,128) -> Ps idx = R+1+w (j = i-127+w)
  for (int R = 0; R < 16; R++) {
    int row = (b * 16 + h) * 2048 + qb + R;
    unsigned short p0 = Ps[wave][R * PSS + R + 1 + lane * 2];
    unsigned short p1 = Ps[wave][R * PSS + R + 2 + lane * 2];
    ((unsigned*)cb)[row * 64 + lane] = (unsigned)p0 | ((unsigned)p1 << 16);
  }
}

// ---------------- dense weights writer: pure streaming ----------------
// wout rows [65536][2048] fp32; band from cb. 16 rows/block (4/wave).
__global__ __launch_bounds__(256) void k_wwrite(const unsigned short* __restrict__ cb,
                                                float* __restrict__ wout) {
  int tid = threadIdx.x, wave = tid >> 6, lane = tid & 63;
  int rbase = blockIdx.x * 16 + wave * 4;
  for (int rr = 0; rr < 4; rr++) {
    int row = rbase + rr;
    int i = row & 2047;
    float* rowp = wout + (size_t)row * 2048;
    const unsigned short* crow = cb + (size_t)row * 128;
    int lo = i - 127;
#pragma unroll
    for (int it = 0; it < 8; it++) {
      int col = it * 256 + lane * 4;
      float4 v = {0.f, 0.f, 0.f, 0.f};
      if (col <= i && col + 3 >= lo) {
#pragma unroll
        for (int e = 0; e < 4; e++) {
          int j = col + e;
          if (j >= lo && j <= i && j >= 0)
            (&v.x)[e] = bf2f(crow[j - lo]);
        }
      }
      *(float4*)(rowp + col) = v;
    }
  }
}

// ---------------- host launch ----------------
extern "C" void kernel_launch(void* const* d_in, const int* in_sizes, int n_in,
                              void* d_out, int out_size, void* d_ws, size_t ws_size,
                              hipStream_t stream) {
  (void)in_sizes; (void)n_in; (void)out_size; (void)ws_size;
  const float* x  = (const float*)d_in[0];
  const float* Wq = (const float*)d_in[1];
  const float* bq = (const float*)d_in[2];
  const float* Wk = (const float*)d_in[3];
  const float* bk = (const float*)d_in[4];
  const float* Wv = (const float*)d_in[5];
  const float* bv = (const float*)d_in[6];
  const float* Wo = (const float*)d_in[7];
  const float* bo = (const float*)d_in[8];

  char* ws = (char*)d_ws;
  unsigned short* xb   = (unsigned short*)(ws);                  //  8,388,608 B
  unsigned short* WT   = (unsigned short*)(ws + 8388608);        //  6,291,456 B  [3072][1024]
  unsigned short* WoT  = (unsigned short*)(ws + 14680064);       //  2,097,152 B  [1024][1024]
  float*          bqkv = (float*)(ws + 16777216);                //     12,288 B
  unsigned short* QKV  = (unsigned short*)(ws + 16789504);       // 25,165,824 B  [4096][3072]
  unsigned short* Oat  = (unsigned short*)(ws + 41955328);       //  8,388,608 B  [4096][1024]
  unsigned short* cb   = (unsigned short*)(ws + 50343936);       // 16,777,216 B  [65536][128]

  float* out  = (float*)d_out;          // [2,2048,1024]
  float* wout = out + 4194304;          // [2,16,2048,2048]

  k_cvt_x<<<4096, 256, 0, stream>>>(x, xb);
  k_trans_w4<<<dim3(32, 32, 4), 256, 0, stream>>>(Wq, Wk, Wv, Wo, WT, WoT);
  k_bias<<<12, 256, 0, stream>>>(bq, bk, bv, bqkv);
  k_gemm<false><<<dim3(24, 32), 256, 0, stream>>>(xb, WT, bqkv, QKV, 3072);
  k_attn<<<dim3(32, 16, 2), 256, 0, stream>>>(QKV, Oat, cb);
  k_wwrite<<<4096, 256, 0, stream>>>(cb, wout);
  k_gemm<true><<<dim3(8, 32), 256, 0, stream>>>(Oat, WoT, bo, out, 1024);
}

// Round 5
// 641.610 us; speedup vs baseline: 1.0699x; 1.0699x over previous
//
#include <hip/hip_runtime.h>
#include <cmath>

typedef __attribute__((ext_vector_type(8))) __bf16 v8bf;
typedef __attribute__((ext_vector_type(4))) float  v4f;

#define DEV static __device__ __forceinline__

DEV unsigned short f2bf(float f) {
  unsigned u = __builtin_bit_cast(unsigned, f);
  unsigned r = u + 0x7fffu + ((u >> 16) & 1u);   // RNE
  return (unsigned short)(r >> 16);
}
DEV float bf2f(unsigned short s) {
  return __builtin_bit_cast(float, ((unsigned)s) << 16);
}
DEV v8bf ld8(const unsigned short* p) { return *(const v8bf*)p; }

// async global->LDS, 16 B per lane; LDS dest = wave-uniform base + lane*16
DEV void gl16(const unsigned short* g, unsigned short* l) {
  __builtin_amdgcn_global_load_lds(
      (const __attribute__((address_space(1))) unsigned int*)g,
      (__attribute__((address_space(3))) unsigned int*)l, 16, 0, 0);
}

// ---------------- fused prep: cvt_x | weight transpose | bias pack ----------------
// grid 8204: [0,4096) cvt_x, [4096,8192) trans (4 matrices x 1024 tiles), [8192,8204) bias
__global__ __launch_bounds__(256) void k_prep(const float* __restrict__ x,
                                              const float* __restrict__ Wq,
                                              const float* __restrict__ Wk,
                                              const float* __restrict__ Wv,
                                              const float* __restrict__ Wo,
                                              const float* __restrict__ bq,
                                              const float* __restrict__ bk,
                                              const float* __restrict__ bv,
                                              unsigned short* __restrict__ xb,
                                              unsigned short* __restrict__ WT,
                                              unsigned short* __restrict__ WoT,
                                              float* __restrict__ bqkv) {
  __shared__ float t[32][33];
  int bx = blockIdx.x, tid = threadIdx.x;
  if (bx < 4096) {                               // x fp32 -> bf16, 4 elems/thread
    int i = bx * 256 + tid;
    float4 v = ((const float4*)x)[i];
    unsigned lo = (unsigned)f2bf(v.x) | ((unsigned)f2bf(v.y) << 16);
    unsigned hi = (unsigned)f2bf(v.z) | ((unsigned)f2bf(v.w) << 16);
    ((uint2*)xb)[i] = make_uint2(lo, hi);
  } else if (bx < 8192) {                        // W[k][n] -> WT[n][k] bf16
    int rem = bx - 4096;
    int z = rem >> 10, r2 = rem & 1023;
    const float* src = (z == 0) ? Wq : (z == 1) ? Wk : (z == 2) ? Wv : Wo;
    unsigned short* dst = (z < 3) ? WT + z * 1048576 : WoT;
    int n0 = (r2 & 31) * 32, k0 = (r2 >> 5) * 32;
    int tx = tid & 31, ty = tid >> 5;
    for (int r = ty; r < 32; r += 8)
      t[r][tx] = src[(k0 + r) * 1024 + n0 + tx];
    __syncthreads();
    for (int r = ty; r < 32; r += 8)
      dst[(n0 + r) * 1024 + k0 + tx] = f2bf(t[tx][r]);
  } else {                                       // bias concat
    int i = (bx - 8192) * 256 + tid;
    float v = (i < 1024) ? bq[i] : (i < 2048 ? bk[i - 1024] : bv[i - 2048]);
    bqkv[i] = v;
  }
}

// ---------------- bf16 MFMA GEMM (m97 structure): C = A * Bt^T + bias ----------------
// 128x128 tile, BK=32, global_load_lds width-16 staging, 4 waves each 64x64.
__global__ __launch_bounds__(256) void k_gemm1(const unsigned short* __restrict__ A,
                                               const unsigned short* __restrict__ Bt,
                                               const float* __restrict__ bias,
                                               unsigned short* __restrict__ Cout) {
  constexpr int K = 1024;
  __shared__ __attribute__((aligned(16))) unsigned short As[128 * 32];
  __shared__ __attribute__((aligned(16))) unsigned short Bs[128 * 32];
  int tid = threadIdx.x;
  int wave = tid >> 6, lane = tid & 63;
  int m0 = blockIdx.y * 128, n0 = blockIdx.x * 128;
  int wm = (wave >> 1) * 64, wn = (wave & 1) * 64;
  int m = lane & 15, q4 = lane >> 4;
  int arow = tid >> 2, acol = (tid & 3) * 8;
  v4f acc[4][4] = {};
  const unsigned short* ga0 = A + (m0 + arow) * K + acol;
  const unsigned short* ga1 = A + (m0 + 64 + arow) * K + acol;
  const unsigned short* gb0 = Bt + (n0 + arow) * K + acol;
  const unsigned short* gb1 = Bt + (n0 + 64 + arow) * K + acol;
  unsigned short* lA0 = As + wave * 512;
  unsigned short* lA1 = As + 2048 + wave * 512;
  unsigned short* lB0 = Bs + wave * 512;
  unsigned short* lB1 = Bs + 2048 + wave * 512;

  for (int kt = 0; kt < K; kt += 32) {
    gl16(ga0 + kt, lA0);
    gl16(ga1 + kt, lA1);
    gl16(gb0 + kt, lB0);
    gl16(gb1 + kt, lB1);
    __syncthreads();
    v8bf af[4], bfv[4];
#pragma unroll
    for (int mt = 0; mt < 4; mt++) af[mt] = ld8(&As[(wm + mt * 16 + m) * 32 + q4 * 8]);
#pragma unroll
    for (int nt = 0; nt < 4; nt++) bfv[nt] = ld8(&Bs[(wn + nt * 16 + m) * 32 + q4 * 8]);
#pragma unroll
    for (int mt = 0; mt < 4; mt++)
#pragma unroll
      for (int nt = 0; nt < 4; nt++)
        acc[mt][nt] = __builtin_amdgcn_mfma_f32_16x16x32_bf16(af[mt], bfv[nt], acc[mt][nt], 0, 0, 0);
    __syncthreads();
  }
#pragma unroll
  for (int mt = 0; mt < 4; mt++)
#pragma unroll
    for (int nt = 0; nt < 4; nt++) {
      int col = n0 + wn + nt * 16 + m;
      float bb = bias[col];
#pragma unroll
      for (int r = 0; r < 4; r++) {
        int row = m0 + wm + mt * 16 + q4 * 4 + r;
        Cout[row * 3072 + col] = f2bf(acc[mt][nt][r] + bb);
      }
    }
}

// ---------------- V transpose: Vtg[(b*16+h)*64 + d][2048] = V[b][s][h][d] ----------------
// grid 4096 flat: bh (32) x d-half (2) x s-tile (64). 32x32 LDS tile.
__global__ __launch_bounds__(256) void k_transv(const unsigned short* __restrict__ QKV,
                                                unsigned short* __restrict__ Vtg) {
  __shared__ unsigned short t[32][33];
  int bx = blockIdx.x, tid = threadIdx.x;
  int st = bx & 63, h2 = (bx >> 6) & 1, bh = bx >> 7;
  int b = bh >> 4, h = bh & 15;
  int s0 = st * 32, d0 = h2 * 32;
  int tx = tid & 31, ty = tid >> 5;
  const unsigned short* src = QKV + (size_t)b * 2048 * 3072 + 2048 + h * 64 + d0;
  for (int r = ty; r < 32; r += 8)
    t[r][tx] = src[(size_t)(s0 + r) * 3072 + tx];
  __syncthreads();
  unsigned short* dst = Vtg + (size_t)(bh * 64 + d0) * 2048 + s0;
  for (int r = ty; r < 32; r += 8)
    dst[(size_t)r * 2048 + tx] = t[tx][r];
}

// ---------------- sliding-window attention (band only) ----------------
// One block = (b, h, 64 queries), 4 waves x 16 q. Writes Oatt bf16 and band cb bf16.
__global__ __launch_bounds__(256) void k_attn(const unsigned short* __restrict__ QKV,
                                              const unsigned short* __restrict__ Vtg,
                                              unsigned short* __restrict__ Oatt,
                                              unsigned short* __restrict__ cb) {
  constexpr int VTS = 208;
  constexpr int PSS = 168;
  __shared__ __attribute__((aligned(16))) unsigned short Vt[64 * VTS];
  __shared__ __attribute__((aligned(16))) unsigned short Ps[4][16 * PSS];
  int b = blockIdx.z, h = blockIdx.y, i0 = blockIdx.x * 64;
  int tid = threadIdx.x, wave = tid >> 6, lane = tid & 63;
  int kbase = i0 - 128;
  const int ld = 3072;
  const unsigned short* Qg = QKV + b * 2048 * ld + h * 64;
  const unsigned short* Kg = Qg + 1024;

  // stage V from pre-transposed Vtg: 64 d-rows x 192 keys, b128 both sides
  const unsigned short* vsrc = Vtg + (size_t)(b * 16 + h) * 64 * 2048;
  for (int idx = tid; idx < 1536; idx += 256) {
    int row = idx / 24, c16 = idx % 24;
    int gcol = kbase + c16 * 8;
    if (gcol < 0) gcol = 0;                       // clamp; P mask zeroes these keys
    v8bf vv = ld8(vsrc + (size_t)row * 2048 + gcol);
    *(v8bf*)&Vt[row * VTS + c16 * 8] = vv;
  }
  // zero Vt cols [192,208): wave3's PV c=4 chunk reads them
  {
    int row = tid >> 2, c4 = (tid & 3) * 4;
    *(uint2*)&Vt[row * VTS + 192 + c4] = make_uint2(0u, 0u);
  }
  // zero Ps pad cols [144,168)
  for (int c = lane; c < 16 * 24; c += 64)
    Ps[wave][(c / 24) * PSS + 144 + (c % 24)] = 0;
  __syncthreads();

  int qb = i0 + wave * 16;
  int m = lane & 15, q4 = lane >> 4;

  const unsigned short* qrow = Qg + (qb + m) * ld;
  v8bf qa0 = ld8(qrow + q4 * 8);
  v8bf qa1 = ld8(qrow + 32 + q4 * 8);

  v4f sc[9];
#pragma unroll
  for (int n = 0; n < 9; n++) {
    int key = kbase + wave * 16 + n * 16 + m;
    int kg = key < 0 ? 0 : key;
    const unsigned short* krow = Kg + kg * ld;
    v8bf kb0 = ld8(krow + q4 * 8);
    v8bf kb1 = ld8(krow + 32 + q4 * 8);
    v4f z = {0.f, 0.f, 0.f, 0.f};
    z = __builtin_amdgcn_mfma_f32_16x16x32_bf16(qa0, kb0, z, 0, 0, 0);
    z = __builtin_amdgcn_mfma_f32_16x16x32_bf16(qa1, kb1, z, 0, 0, 0);
    sc[n] = z;
  }
  float mx[4] = {-3e38f, -3e38f, -3e38f, -3e38f};
#pragma unroll
  for (int n = 0; n < 9; n++)
#pragma unroll
    for (int r = 0; r < 4; r++) {
      int i = qb + q4 * 4 + r;
      int j = kbase + wave * 16 + n * 16 + m;
      float v = sc[n][r] * 0.125f;
      bool ok = (j >= 0) && (j <= i) && (j > i - 128);
      v = ok ? v : -3e38f;
      sc[n][r] = v;
      mx[r] = fmaxf(mx[r], v);
    }
#pragma unroll
  for (int o = 1; o < 16; o <<= 1)
#pragma unroll
    for (int r = 0; r < 4; r++) mx[r] = fmaxf(mx[r], __shfl_xor(mx[r], o, 64));
  float sum[4] = {0.f, 0.f, 0.f, 0.f};
#pragma unroll
  for (int n = 0; n < 9; n++)
#pragma unroll
    for (int r = 0; r < 4; r++) {
      float p = __expf(sc[n][r] - mx[r]);
      sc[n][r] = p;
      sum[r] += p;
    }
#pragma unroll
  for (int o = 1; o < 16; o <<= 1)
#pragma unroll
    for (int r = 0; r < 4; r++) sum[r] += __shfl_xor(sum[r], o, 64);
  float inv[4];
#pragma unroll
  for (int r = 0; r < 4; r++) inv[r] = 1.0f / sum[r];

#pragma unroll
  for (int n = 0; n < 9; n++)
#pragma unroll
    for (int r = 0; r < 4; r++)
      Ps[wave][(q4 * 4 + r) * PSS + n * 16 + m] = f2bf(sc[n][r] * inv[r]);
  __syncthreads();

  v4f oacc[4] = {};
#pragma unroll
  for (int c = 0; c < 5; c++) {
    v8bf pa = ld8(&Ps[wave][m * PSS + c * 32 + q4 * 8]);
#pragma unroll
    for (int dt = 0; dt < 4; dt++) {
      v8bf vb = ld8(&Vt[(dt * 16 + m) * VTS + wave * 16 + c * 32 + q4 * 8]);
      oacc[dt] = __builtin_amdgcn_mfma_f32_16x16x32_bf16(pa, vb, oacc[dt], 0, 0, 0);
    }
  }
#pragma unroll
  for (int dt = 0; dt < 4; dt++)
#pragma unroll
    for (int r = 0; r < 4; r++)
      Oatt[(b * 2048 + qb + q4 * 4 + r) * 1024 + h * 64 + dt * 16 + m] = f2bf(oacc[dt][r]);

  for (int R = 0; R < 16; R++) {
    int row = (b * 16 + h) * 2048 + qb + R;
    unsigned short p0 = Ps[wave][R * PSS + R + 1 + lane * 2];
    unsigned short p1 = Ps[wave][R * PSS + R + 2 + lane * 2];
    ((unsigned*)cb)[row * 64 + lane] = (unsigned)p0 | ((unsigned)p1 << 16);
  }
}

// ---------------- fused tail: out-proj GEMM (blocks 0..255) + dense-weights writer ----------------
// Both depend only on k_attn; gemm blocks first so MFMA work hides under the 537 MB write.
__global__ __launch_bounds__(256) void k_tail(const unsigned short* __restrict__ Oat,
                                              const unsigned short* __restrict__ WoT,
                                              const float* __restrict__ bo,
                                              float* __restrict__ out,
                                              const unsigned short* __restrict__ cb,
                                              float* __restrict__ wout) {
  __shared__ __attribute__((aligned(16))) unsigned short As[128 * 32];
  __shared__ __attribute__((aligned(16))) unsigned short Bs[128 * 32];
  int tid = threadIdx.x, wave = tid >> 6, lane = tid & 63;

  if (blockIdx.x < 256) {
    // ---- gemm role: out[4096][1024] = Oat[4096][1024] x WoT^T + bo
    constexpr int K = 1024;
    int bx = blockIdx.x;
    int n0 = (bx & 7) * 128, m0 = (bx >> 3) * 128;
    int wm = (wave >> 1) * 64, wn = (wave & 1) * 64;
    int m = lane & 15, q4 = lane >> 4;
    int arow = tid >> 2, acol = (tid & 3) * 8;
    v4f acc[4][4] = {};
    const unsigned short* ga0 = Oat + (m0 + arow) * K + acol;
    const unsigned short* ga1 = Oat + (m0 + 64 + arow) * K + acol;
    const unsigned short* gb0 = WoT + (n0 + arow) * K + acol;
    const unsigned short* gb1 = WoT + (n0 + 64 + arow) * K + acol;
    unsigned short* lA0 = As + wave * 512;
    unsigned short* lA1 = As + 2048 + wave * 512;
    unsigned short* lB0 = Bs + wave * 512;
    unsigned short* lB1 = Bs + 2048 + wave * 512;
    for (int kt = 0; kt < K; kt += 32) {
      gl16(ga0 + kt, lA0);
      gl16(ga1 + kt, lA1);
      gl16(gb0 + kt, lB0);
      gl16(gb1 + kt, lB1);
      __syncthreads();
      v8bf af[4], bfv[4];
#pragma unroll
      for (int mt = 0; mt < 4; mt++) af[mt] = ld8(&As[(wm + mt * 16 + m) * 32 + q4 * 8]);
#pragma unroll
      for (int nt = 0; nt < 4; nt++) bfv[nt] = ld8(&Bs[(wn + nt * 16 + m) * 32 + q4 * 8]);
#pragma unroll
      for (int mt = 0; mt < 4; mt++)
#pragma unroll
        for (int nt = 0; nt < 4; nt++)
          acc[mt][nt] = __builtin_amdgcn_mfma_f32_16x16x32_bf16(af[mt], bfv[nt], acc[mt][nt], 0, 0, 0);
      __syncthreads();
    }
#pragma unroll
    for (int mt = 0; mt < 4; mt++)
#pragma unroll
      for (int nt = 0; nt < 4; nt++) {
        int col = n0 + wn + nt * 16 + m;
        float bb = bo[col];
#pragma unroll
        for (int r = 0; r < 4; r++) {
          int row = m0 + wm + mt * 16 + q4 * 4 + r;
          out[row * 1024 + col] = acc[mt][nt][r] + bb;
        }
      }
  } else {
    // ---- writer role: dense weights rows, nontemporal streaming stores
    int wb = blockIdx.x - 256;
    int rbase = wb * 16 + wave * 4;
    for (int rr = 0; rr < 4; rr++) {
      int row = rbase + rr;
      int i = row & 2047;
      float* rowp = wout + (size_t)row * 2048;
      const unsigned short* crow = cb + (size_t)row * 128;
      int lo = i - 127;
#pragma unroll
      for (int it = 0; it < 8; it++) {
        int col = it * 256 + lane * 4;
        v4f v = {0.f, 0.f, 0.f, 0.f};             // clang vector type: valid for
        if (col <= i && col + 3 >= lo) {          // __builtin_nontemporal_store
#pragma unroll
          for (int e = 0; e < 4; e++) {
            int j = col + e;
            if (j >= lo && j <= i && j >= 0)
              v[e] = bf2f(crow[j - lo]);
          }
        }
        __builtin_nontemporal_store(v, (v4f*)(rowp + col));
      }
    }
  }
}

// ---------------- host launch ----------------
extern "C" void kernel_launch(void* const* d_in, const int* in_sizes, int n_in,
                              void* d_out, int out_size, void* d_ws, size_t ws_size,
                              hipStream_t stream) {
  (void)in_sizes; (void)n_in; (void)out_size; (void)ws_size;
  const float* x  = (const float*)d_in[0];
  const float* Wq = (const float*)d_in[1];
  const float* bq = (const float*)d_in[2];
  const float* Wk = (const float*)d_in[3];
  const float* bk = (const float*)d_in[4];
  const float* Wv = (const float*)d_in[5];
  const float* bv = (const float*)d_in[6];
  const float* Wo = (const float*)d_in[7];
  const float* bo = (const float*)d_in[8];

  char* ws = (char*)d_ws;
  unsigned short* xb   = (unsigned short*)(ws);                  //  8,388,608 B
  unsigned short* WT   = (unsigned short*)(ws + 8388608);        //  6,291,456 B  [3072][1024]
  unsigned short* WoT  = (unsigned short*)(ws + 14680064);       //  2,097,152 B  [1024][1024]
  float*          bqkv = (float*)(ws + 16777216);                //     12,288 B
  unsigned short* QKV  = (unsigned short*)(ws + 16789504);       // 25,165,824 B  [4096][3072]
  unsigned short* Oat  = (unsigned short*)(ws + 41955328);       //  8,388,608 B  [4096][1024]
  unsigned short* cb   = (unsigned short*)(ws + 50343936);       // 16,777,216 B  [65536][128]
  unsigned short* Vtg  = (unsigned short*)(ws + 67121152);       //  8,388,608 B  [2048][2048]

  float* out  = (float*)d_out;          // [2,2048,1024]
  float* wout = out + 4194304;          // [2,16,2048,2048]

  k_prep<<<8204, 256, 0, stream>>>(x, Wq, Wk, Wv, Wo, bq, bk, bv, xb, WT, WoT, bqkv);
  k_gemm1<<<dim3(24, 32), 256, 0, stream>>>(xb, WT, bqkv, QKV);
  k_transv<<<4096, 256, 0, stream>>>(QKV, Vtg);
  k_attn<<<dim3(32, 16, 2), 256, 0, stream>>>(QKV, Vtg, Oat, cb);
  k_tail<<<4352, 256, 0, stream>>>(Oat, WoT, bo, out, cb, wout);
}